// Round 3
// baseline (247.465 us; speedup 1.0000x reference)
//
#include <hip/hip_runtime.h>

// Causal flash attention, B=4 H=16 S=2048 D=64, fp32 in/out, bf16 MFMA.
// R3: 64 q-rows per wave (256 per block, grid=512). K-frags held in registers
// across 4 m-tiles; V-frags shared across m-tiles => per-q-row LDS traffic
// halves vs R2 (the R2 bottleneck: all 4 waves re-read identical K/V frags).
// Heavy+light block pairing for the 2-blocks/CU residency. Pre-pass converts
// K/V to bf16 swizzled tile images in d_ws; DMA staging via global_load_lds.

#define S_LEN 2048
#define D_HEAD 64
#define NBH 64      // B*H
#define QBLK 32     // S / 64 (64-row granules)
#define TILE_E 4096 // 64x64 elements per tile image

typedef float f32x4 __attribute__((ext_vector_type(4)));
typedef short s16x8 __attribute__((ext_vector_type(8)));

#define SCLOG2E (0.125f * 1.44269504088896340736f)  // 1/sqrt(D) * log2(e)

__device__ __forceinline__ unsigned short f2bf(float x) {  // RNE
    union { float f; unsigned int u; } v; v.f = x;
    unsigned int u = v.u + 0x7FFFu + ((v.u >> 16) & 1u);
    return (unsigned short)(u >> 16);
}
__device__ __forceinline__ unsigned short f2bf_hu(float x) { // half-up (P path)
    union { float f; unsigned int u; } v; v.f = x;
    return (unsigned short)((v.u + 0x8000u) >> 16);
}

// chunk-rotation swizzle (verified: 0 read bank conflicts)
__device__ __forceinline__ int swz(int row, int col) {
    return row * 64 + ((((col >> 3) + row) & 7) << 3) + (col & 7);
}

__device__ __forceinline__ void g2l(const unsigned short* g, unsigned short* l) {
    __builtin_amdgcn_global_load_lds(
        (const __attribute__((address_space(1))) void*)g,
        (__attribute__((address_space(3))) void*)l, 16, 0, 0);
}

// ---------- pre-pass: fp32 K,V -> bf16 swizzled tile images in workspace ----
__global__ __launch_bounds__(256)
void preconv_kernel(const float* __restrict__ K, const float* __restrict__ V,
                    unsigned short* __restrict__ Kw, unsigned short* __restrict__ Vw)
{
    __shared__ __align__(16) unsigned short kt[TILE_E];
    __shared__ __align__(16) unsigned short vt[TILE_E];
    const int bh = blockIdx.x & (NBH - 1);
    const int j  = blockIdx.x >> 6;
    const float* k = K + (size_t)bh * (S_LEN * D_HEAD) + (size_t)j * 64 * D_HEAD;
    const float* v = V + (size_t)bh * (S_LEN * D_HEAD) + (size_t)j * 64 * D_HEAD;
    const int t = threadIdx.x;

#pragma unroll
    for (int i = 0; i < 2; ++i) {   // K tile, row-major [key][d], swizzled
        int chunk = t + 256 * i;
        int row = chunk >> 3, c = chunk & 7;
        const float* p = k + (size_t)row * D_HEAD + c * 8;
        float4 x = *(const float4*)p;
        float4 y = *(const float4*)(p + 4);
        s16x8 f;
        f[0] = (short)f2bf(x.x); f[1] = (short)f2bf(x.y);
        f[2] = (short)f2bf(x.z); f[3] = (short)f2bf(x.w);
        f[4] = (short)f2bf(y.x); f[5] = (short)f2bf(y.y);
        f[6] = (short)f2bf(y.z); f[7] = (short)f2bf(y.w);
        *(s16x8*)&kt[swz(row, c * 8)] = f;
    }
    {   // V tile, transposed [d][key], swizzled (scalar writes conflict-free)
        int key = t & 63, cc = t >> 6;
#pragma unroll
        for (int ci = 0; ci < 2; ++ci) {
            int c = cc + ci * 4;
            const float* p = v + (size_t)key * D_HEAD + c * 8;
            float4 x = *(const float4*)p;
            float4 y = *(const float4*)(p + 4);
            float vals[8] = {x.x, x.y, x.z, x.w, y.x, y.y, y.z, y.w};
#pragma unroll
            for (int jj = 0; jj < 8; ++jj)
                vt[swz(c * 8 + jj, key)] = f2bf(vals[jj]);
        }
    }
    __syncthreads();
    const size_t tb = (size_t)(bh * QBLK + j) * TILE_E;
#pragma unroll
    for (int i = 0; i < 2; ++i) {
        int idx = (t + 256 * i) * 8;
        *(s16x8*)&Kw[tb + idx] = *(const s16x8*)&kt[idx];
        *(s16x8*)&Vw[tb + idx] = *(const s16x8*)&vt[idx];
    }
}

// ---------------------------- main kernel -----------------------------------
template <bool PRE>
__global__ __launch_bounds__(256, 2)
void fattn_kernel(const float* __restrict__ Qg, const float* __restrict__ Kg,
                  const float* __restrict__ Vg, float* __restrict__ Og,
                  const unsigned short* __restrict__ Kw,
                  const unsigned short* __restrict__ Vw)
{
    __shared__ __align__(16) unsigned short ks[2][TILE_E];
    __shared__ __align__(16) unsigned short vs[2][TILE_E];
    __shared__ __align__(16) unsigned short ps[4][TILE_E];  // per-wave 64x64 P

    const int bx = blockIdx.x;
    const int bh = bx & (NBH - 1);
    // heavy+light pairing: first 256 blocks b in {4..7}, partner gets 7-b
    const int sub = (bx >> 6) & 3;
    const int b   = (bx < 256) ? (4 + sub) : (3 - sub);
    const size_t base = (size_t)bh * (S_LEN * D_HEAD);
    const float* q = Qg + base;
    const float* k = Kg + base;
    const float* v = Vg + base;
    float*       o = Og + base;

    const int t    = threadIdx.x;
    const int w    = t >> 6;
    const int lane = t & 63;
    const int col  = lane & 15;
    const int quad = lane >> 4;

    // Q fragments (A-layout): 4 m-tiles x 2 k-halves, fp32->bf16 once
    s16x8 qa[4][2];
#pragma unroll
    for (int m = 0; m < 4; ++m) {
        const int qr = b * 256 + w * 64 + m * 16 + col;
        const float* p0 = q + (size_t)qr * D_HEAD + quad * 8;
#pragma unroll
        for (int kt2 = 0; kt2 < 2; ++kt2) {
            const float* p = p0 + kt2 * 32;
            float4 x = *(const float4*)(p);
            float4 y = *(const float4*)(p + 4);
            s16x8 f;
            f[0] = (short)f2bf(x.x); f[1] = (short)f2bf(x.y);
            f[2] = (short)f2bf(x.z); f[3] = (short)f2bf(x.w);
            f[4] = (short)f2bf(y.x); f[5] = (short)f2bf(y.y);
            f[6] = (short)f2bf(y.z); f[7] = (short)f2bf(y.w);
            qa[m][kt2] = f;
        }
    }

    s16x8 ones;
#pragma unroll
    for (int i = 0; i < 8; ++i) ones[i] = (short)0x3F80;  // bf16 1.0

    f32x4 oacc[4][4], lf[4];
#pragma unroll
    for (int m = 0; m < 4; ++m) {
        lf[m] = (f32x4){0.f, 0.f, 0.f, 0.f};
#pragma unroll
        for (int nt = 0; nt < 4; ++nt) oacc[m][nt] = (f32x4){0.f, 0.f, 0.f, 0.f};
    }

    auto stage = [&](int jt, int buf) {
        if constexpr (PRE) {
            const size_t tb = (size_t)(bh * QBLK + jt) * TILE_E;
#pragma unroll
            for (int i = 0; i < 2; ++i) {
                int c = w * 2 + i;
                g2l(Kw + tb + c * 512 + lane * 8, &ks[buf][c * 512]);
                g2l(Vw + tb + c * 512 + lane * 8, &vs[buf][c * 512]);
            }
        } else {
            const int kb = jt * 64;
#pragma unroll
            for (int i = 0; i < 2; ++i) {
                int chunk = t + 256 * i;
                int row = chunk >> 3, c = chunk & 7;
                const float* p = k + (size_t)(kb + row) * D_HEAD + c * 8;
                float4 x = *(const float4*)p;
                float4 y = *(const float4*)(p + 4);
                s16x8 f;
                f[0] = (short)f2bf(x.x); f[1] = (short)f2bf(x.y);
                f[2] = (short)f2bf(x.z); f[3] = (short)f2bf(x.w);
                f[4] = (short)f2bf(y.x); f[5] = (short)f2bf(y.y);
                f[6] = (short)f2bf(y.z); f[7] = (short)f2bf(y.w);
                *(s16x8*)&ks[buf][swz(row, c * 8)] = f;
            }
            int key = t & 63, cc = t >> 6;
#pragma unroll
            for (int ci = 0; ci < 2; ++ci) {
                int c = cc + ci * 4;
                const float* p = v + (size_t)(kb + key) * D_HEAD + c * 8;
                float4 x = *(const float4*)p;
                float4 y = *(const float4*)(p + 4);
                float vals[8] = {x.x, x.y, x.z, x.w, y.x, y.y, y.z, y.w};
#pragma unroll
                for (int jj = 0; jj < 8; ++jj)
                    vs[buf][swz(c * 8 + jj, key)] = f2bf(vals[jj]);
            }
        }
    };

    stage(0, 0);
    const int jmax = 4 * b + 3;

    for (int j = 0; j <= jmax; ++j) {
        const int cur = j & 1;
        __syncthreads();                 // drains prefetch DMA + guards reuse
        if (j < jmax) stage(j + 1, 1 - cur);

        // ---- K B-frags once per tile, reused by all 4 m-tiles
        s16x8 kb2[2][4];
#pragma unroll
        for (int kt2 = 0; kt2 < 2; ++kt2)
#pragma unroll
            for (int nt = 0; nt < 4; ++nt)
                kb2[kt2][nt] = *(const s16x8*)&ks[cur][swz(nt * 16 + col, (4 * kt2 + quad) * 8)];

        const bool diag = (j >= 4 * b);
#pragma unroll
        for (int m = 0; m < 4; ++m) {
            f32x4 sf[4];
#pragma unroll
            for (int nt = 0; nt < 4; ++nt) sf[nt] = (f32x4){0.f, 0.f, 0.f, 0.f};
#pragma unroll
            for (int kt2 = 0; kt2 < 2; ++kt2)
#pragma unroll
                for (int nt = 0; nt < 4; ++nt)
                    sf[nt] = __builtin_amdgcn_mfma_f32_16x16x32_bf16(qa[m][kt2], kb2[kt2][nt], sf[nt], 0, 0, 0);

            if (diag) {
                const int qrl = b * 256 + w * 64 + m * 16 + quad * 4;
#pragma unroll
                for (int nt = 0; nt < 4; ++nt) {
                    const int keyl = j * 64 + nt * 16 + col;
#pragma unroll
                    for (int r = 0; r < 4; ++r)
                        sf[nt][r] = (keyl > qrl + r) ? -__builtin_inff() : sf[nt][r] * SCLOG2E;
                }
            } else {
#pragma unroll
                for (int nt = 0; nt < 4; ++nt)
#pragma unroll
                    for (int r = 0; r < 4; ++r) sf[nt][r] *= SCLOG2E;
            }
#pragma unroll
            for (int nt = 0; nt < 4; ++nt)
#pragma unroll
                for (int r = 0; r < 4; ++r)
                    ps[w][swz(m * 16 + quad * 4 + r, nt * 16 + col)] = f2bf_hu(exp2f(sf[nt][r]));
        }
        // per-wave LDS region; in-wave DS ordering — no barrier needed

        // ---- P A-frags (4 m x 2 k-halves), then PV with V-frags shared over m
        s16x8 af[4][2];
#pragma unroll
        for (int m = 0; m < 4; ++m)
#pragma unroll
            for (int kt2 = 0; kt2 < 2; ++kt2)
                af[m][kt2] = *(const s16x8*)&ps[w][swz(m * 16 + col, (4 * kt2 + quad) * 8)];

#pragma unroll
        for (int kt2 = 0; kt2 < 2; ++kt2)
#pragma unroll
            for (int nt = 0; nt < 4; ++nt) {
                s16x8 bf = *(const s16x8*)&vs[cur][swz(nt * 16 + col, (4 * kt2 + quad) * 8)];
#pragma unroll
                for (int m = 0; m < 4; ++m)
                    oacc[m][nt] = __builtin_amdgcn_mfma_f32_16x16x32_bf16(af[m][kt2], bf, oacc[m][nt], 0, 0, 0);
            }
#pragma unroll
        for (int m = 0; m < 4; ++m)
#pragma unroll
            for (int kt2 = 0; kt2 < 2; ++kt2)
                lf[m] = __builtin_amdgcn_mfma_f32_16x16x32_bf16(af[m][kt2], ones, lf[m], 0, 0, 0);
    }

    // ---- epilogue
#pragma unroll
    for (int m = 0; m < 4; ++m)
#pragma unroll
        for (int r = 0; r < 4; ++r) {
            float inv = 1.f / lf[m][r];
            int row = b * 256 + w * 64 + m * 16 + quad * 4 + r;
            float* po = o + (size_t)row * D_HEAD;
#pragma unroll
            for (int nt = 0; nt < 4; ++nt) po[nt * 16 + col] = oacc[m][nt][r] * inv;
        }
}

extern "C" void kernel_launch(void* const* d_in, const int* in_sizes, int n_in,
                              void* d_out, int out_size, void* d_ws, size_t ws_size,
                              hipStream_t stream) {
    const float* q = (const float*)d_in[0];
    const float* k = (const float*)d_in[1];
    const float* v = (const float*)d_in[2];
    float* out = (float*)d_out;

    const size_t kv_elems = (size_t)NBH * QBLK * TILE_E;   // 16 MB each
    if (ws_size >= 2 * kv_elems * sizeof(unsigned short)) {
        unsigned short* Kw = (unsigned short*)d_ws;
        unsigned short* Vw = Kw + kv_elems;
        preconv_kernel<<<dim3(NBH * QBLK), dim3(256), 0, stream>>>(k, v, Kw, Vw);
        fattn_kernel<true><<<dim3(512), dim3(256), 0, stream>>>(q, k, v, out, Kw, Vw);
    } else {
        fattn_kernel<false><<<dim3(512), dim3(256), 0, stream>>>(q, k, v, out, nullptr, nullptr);
    }
}